// Round 1
// baseline (86.514 us; speedup 1.0000x reference)
//
#include <hip/hip_runtime.h>

#define TAPS  21
#define CCH   237
#define CHUNK (TAPS * CCH)   // 4977 floats per (b,t) window, contiguous
#define NCHUNK 16384         // 32 * 512
#define NB_PAD 1248          // padded float4 count per phase table
#define TAB_OFF 32           // float offset of tables in ws (w[21] lives at 0..20)

// ---------------------------------------------------------------------------
// Setup kernel: compute softmax weights w[21] and fill 4 phase-shifted
// expanded weight tables wtab[s][m] (float4) where element e of vec m holds
// w[(h + 4m + e) / 237], h = (4 - s) & 3.  Total 4*1248*16 B ~= 80 KB.
// ---------------------------------------------------------------------------
__global__ void conv_weights_kernel(const float* __restrict__ p3,
                                    const float* __restrict__ p4,
                                    float* __restrict__ wsf) {
    __shared__ float w[TAPS];
    int tid = threadIdx.x;
    if (tid == 0) {
        float a = p3[0], b = p4[0];
        float lg[TAPS];
        float mx = -3.4e38f;
        for (int i = 0; i < TAPS; ++i) {
            float fi = (float)(i + 1);
            lg[i] = a * fi + b * fi * fi;
            mx = fmaxf(mx, lg[i]);
        }
        float s = 0.f;
        for (int i = 0; i < TAPS; ++i) { lg[i] = expf(lg[i] - mx); s += lg[i]; }
        float inv = 1.0f / s;
        for (int i = 0; i < TAPS; ++i) w[i] = lg[i] * inv;
    }
    __syncthreads();
    if (tid < TAPS) wsf[tid] = w[tid];
    for (int idx = tid; idx < 4 * NB_PAD * 4; idx += blockDim.x) {
        int s4 = idx / (NB_PAD * 4);
        int r  = idx - s4 * (NB_PAD * 4);
        int h  = (4 - s4) & 3;
        int q  = h + r;
        wsf[TAB_OFF + idx] = (q < CHUNK) ? w[q / CCH] : 0.f;
    }
}

// ---------------------------------------------------------------------------
// Main kernel: one wave (64 lanes) per chunk. 4 waves / 256-thread block.
// Streaming float4 loads of data + L2-resident float4 weight table, FMA,
// wave shuffle reduce, broadcast-store 237 outputs.
// ---------------------------------------------------------------------------
__global__ __launch_bounds__(256) void conv_main_kernel(
    const float* __restrict__ in,
    const float* __restrict__ wsf,
    float* __restrict__ out) {
    int wid  = threadIdx.x >> 6;
    int lane = threadIdx.x & 63;
    int c    = (blockIdx.x << 2) + wid;          // chunk id, < 16384
    int s    = c & 3;                            // alignment phase
    int h    = (4 - s) & 3;                      // scalar prologue length
    long base = (long)c * CHUNK;
    int nb   = (CHUNK - h) >> 2;                 // float4 body count
    int tail = (CHUNK - h) & 3;                  // scalar tail length

    const float4* in4 = (const float4*)(in + base + h);   // 16B aligned
    const float4* wt4 = (const float4*)(wsf + TAB_OFF + s * (NB_PAD * 4));

    float4 acc = make_float4(0.f, 0.f, 0.f, 0.f);
    for (int m = lane; m < nb; m += 64) {
        float4 x  = in4[m];
        float4 wv = wt4[m];
        acc.x = fmaf(x.x, wv.x, acc.x);
        acc.y = fmaf(x.y, wv.y, acc.y);
        acc.z = fmaf(x.z, wv.z, acc.z);
        acc.w = fmaf(x.w, wv.w, acc.w);
    }
    float sum = acc.x + acc.y + acc.z + acc.w;
    // prologue elements (q < h <= 3 -> tap 0), tail elements (q >= 4974 -> tap 20)
    if (lane < h)    sum += in[base + lane] * wsf[0];
    if (lane < tail) sum += in[base + h + 4 * nb + lane] * wsf[TAPS - 1];

    #pragma unroll
    for (int off = 32; off; off >>= 1) sum += __shfl_xor(sum, off, 64);

    long ob = (long)c * CCH;
    for (int j = lane; j < CCH; j += 64) out[ob + j] = sum;
}

// ---------------------------------------------------------------------------
// Fallback (ws too small): weights in LDS, per-element q/237 via const-div.
// ---------------------------------------------------------------------------
__global__ __launch_bounds__(256) void conv_fallback_kernel(
    const float* __restrict__ in,
    const float* __restrict__ p3,
    const float* __restrict__ p4,
    float* __restrict__ out) {
    __shared__ float w[TAPS];
    if (threadIdx.x == 0) {
        float a = p3[0], b = p4[0];
        float lg[TAPS];
        float mx = -3.4e38f;
        for (int i = 0; i < TAPS; ++i) {
            float fi = (float)(i + 1);
            lg[i] = a * fi + b * fi * fi;
            mx = fmaxf(mx, lg[i]);
        }
        float s = 0.f;
        for (int i = 0; i < TAPS; ++i) { lg[i] = expf(lg[i] - mx); s += lg[i]; }
        float inv = 1.0f / s;
        for (int i = 0; i < TAPS; ++i) w[i] = lg[i] * inv;
    }
    __syncthreads();

    int wid  = threadIdx.x >> 6;
    int lane = threadIdx.x & 63;
    int c    = (blockIdx.x << 2) + wid;
    int s    = c & 3;
    int h    = (4 - s) & 3;
    long base = (long)c * CHUNK;
    int nb   = (CHUNK - h) >> 2;
    int tail = (CHUNK - h) & 3;

    const float4* in4 = (const float4*)(in + base + h);
    float4 acc = make_float4(0.f, 0.f, 0.f, 0.f);
    for (int m = lane; m < nb; m += 64) {
        float4 x = in4[m];
        int q0 = h + 4 * m;
        acc.x = fmaf(x.x, w[(q0 + 0) / CCH], acc.x);
        acc.y = fmaf(x.y, w[(q0 + 1) / CCH], acc.y);
        acc.z = fmaf(x.z, w[(q0 + 2) / CCH], acc.z);
        acc.w = fmaf(x.w, w[(q0 + 3) / CCH], acc.w);
    }
    float sum = acc.x + acc.y + acc.z + acc.w;
    if (lane < h)    sum += in[base + lane] * w[0];
    if (lane < tail) sum += in[base + h + 4 * nb + lane] * w[TAPS - 1];

    #pragma unroll
    for (int off = 32; off; off >>= 1) sum += __shfl_xor(sum, off, 64);

    long ob = (long)c * CCH;
    for (int j = lane; j < CCH; j += 64) out[ob + j] = sum;
}

extern "C" void kernel_launch(void* const* d_in, const int* in_sizes, int n_in,
                              void* d_out, int out_size, void* d_ws, size_t ws_size,
                              hipStream_t stream) {
    const float* in = (const float*)d_in[0];
    const float* p3 = (const float*)d_in[1];
    const float* p4 = (const float*)d_in[2];
    float* out = (float*)d_out;

    size_t need = (size_t)(TAB_OFF + 4 * NB_PAD * 4) * sizeof(float);
    if (ws_size >= need && d_ws != nullptr) {
        float* wsf = (float*)d_ws;
        conv_weights_kernel<<<1, 256, 0, stream>>>(p3, p4, wsf);
        conv_main_kernel<<<NCHUNK / 4, 256, 0, stream>>>(in, wsf, out);
    } else {
        conv_fallback_kernel<<<NCHUNK / 4, 256, 0, stream>>>(in, p3, p4, out);
    }
}

// Round 2
// 77.819 us; speedup vs baseline: 1.1117x; 1.1117x over previous
//
#include <hip/hip_runtime.h>

#define TAPS  21
#define CCH   237
#define CHUNK (TAPS * CCH)   // 4977 floats per (b,t) window, contiguous
#define NCHUNK 16384         // 32 * 512
#define NB_PAD 1248          // padded float4 count per phase table
#define TAB_OFF 32           // float offset of tables in ws (w[21] lives at 0..20)

// ---------------------------------------------------------------------------
// Setup kernel: compute softmax weights w[21] and fill 4 phase-shifted
// expanded weight tables wtab[s][m] (float4) where element e of vec m holds
// w[(h + 4m + e) / 237], h = (4 - s) & 3.  Total 4*1248*16 B ~= 80 KB.
// Launched with several blocks; each recomputes w (cheap) and fills a slice.
// ---------------------------------------------------------------------------
__global__ void conv_weights_kernel(const float* __restrict__ p3,
                                    const float* __restrict__ p4,
                                    float* __restrict__ wsf) {
    __shared__ float w[TAPS];
    int tid = threadIdx.x;
    if (tid == 0) {
        float a = p3[0], b = p4[0];
        float lg[TAPS];
        float mx = -3.4e38f;
        for (int i = 0; i < TAPS; ++i) {
            float fi = (float)(i + 1);
            lg[i] = a * fi + b * fi * fi;
            mx = fmaxf(mx, lg[i]);
        }
        float s = 0.f;
        for (int i = 0; i < TAPS; ++i) { lg[i] = expf(lg[i] - mx); s += lg[i]; }
        float inv = 1.0f / s;
        for (int i = 0; i < TAPS; ++i) w[i] = lg[i] * inv;
    }
    __syncthreads();
    if (blockIdx.x == 0 && tid < TAPS) wsf[tid] = w[tid];
    int stride = blockDim.x * gridDim.x;
    for (int idx = blockIdx.x * blockDim.x + tid; idx < 4 * NB_PAD * 4; idx += stride) {
        int s4 = idx / (NB_PAD * 4);
        int r  = idx - s4 * (NB_PAD * 4);
        int h  = (4 - s4) & 3;
        int q  = h + r;
        wsf[TAB_OFF + idx] = (q < CHUNK) ? w[q / CCH] : 0.f;
    }
}

__device__ __forceinline__ float4 fma4(float4 x, float4 w, float4 a) {
    a.x = fmaf(x.x, w.x, a.x);
    a.y = fmaf(x.y, w.y, a.y);
    a.z = fmaf(x.z, w.z, a.z);
    a.w = fmaf(x.w, w.w, a.w);
    return a;
}

// ---------------------------------------------------------------------------
// Main kernel: one wave (64 lanes) per chunk. 4 waves / 256-thread block.
// nb = (CHUNK - h) >> 2 is 1243 or 1244 for every phase, so strided positions
// lane + 64*it are in-bounds for ALL lanes for it = 0..18 (19 iterations).
// Fully unroll those 19 as 4x4 + 3 to expose deep memory-level parallelism,
// then one predicated iteration (it = 19) covers the rest.
// ---------------------------------------------------------------------------
__global__ __launch_bounds__(256) void conv_main_kernel(
    const float* __restrict__ in,
    const float* __restrict__ wsf,
    float* __restrict__ out) {
    int wid  = threadIdx.x >> 6;
    int lane = threadIdx.x & 63;
    int c    = (blockIdx.x << 2) + wid;          // chunk id, < 16384
    int s    = c & 3;                            // alignment phase
    int h    = (4 - s) & 3;                      // scalar prologue length
    long base = (long)c * CHUNK;
    int nb   = (CHUNK - h) >> 2;                 // float4 body count (1243/1244)
    int tail = (CHUNK - h) & 3;                  // scalar tail length

    const float4* in4 = (const float4*)(in + base + h);   // 16B aligned
    const float4* wt4 = (const float4*)(wsf + TAB_OFF + s * (NB_PAD * 4));

    float4 a0 = make_float4(0.f, 0.f, 0.f, 0.f);
    float4 a1 = a0, a2 = a0, a3 = a0;

    int m = lane;
    #pragma unroll
    for (int g = 0; g < 4; ++g) {                // 16 unconditional iterations
        float4 x0 = in4[m      ];
        float4 x1 = in4[m +  64];
        float4 x2 = in4[m + 128];
        float4 x3 = in4[m + 192];
        float4 w0 = wt4[m      ];
        float4 w1 = wt4[m +  64];
        float4 w2 = wt4[m + 128];
        float4 w3 = wt4[m + 192];
        a0 = fma4(x0, w0, a0);
        a1 = fma4(x1, w1, a1);
        a2 = fma4(x2, w2, a2);
        a3 = fma4(x3, w3, a3);
        m += 256;
    }
    // 3 more unconditional (positions 1024+lane .. 1215)
    {
        float4 x0 = in4[m      ];
        float4 x1 = in4[m +  64];
        float4 x2 = in4[m + 128];
        float4 w0 = wt4[m      ];
        float4 w1 = wt4[m +  64];
        float4 w2 = wt4[m + 128];
        a0 = fma4(x0, w0, a0);
        a1 = fma4(x1, w1, a1);
        a2 = fma4(x2, w2, a2);
        m += 192;                                 // = 1216 + lane
    }
    if (m < nb) a3 = fma4(in4[m], wt4[m], a3);   // final predicated iteration

    a0 = fma4(make_float4(1.f,1.f,1.f,1.f), a1, a0);
    a2 = fma4(make_float4(1.f,1.f,1.f,1.f), a3, a2);
    float sum = (a0.x + a0.y) + (a0.z + a0.w) + (a2.x + a2.y) + (a2.z + a2.w);

    // prologue elements (tap 0) and tail elements (tap 20)
    if (lane < h)    sum += in[base + lane] * wsf[0];
    if (lane < tail) sum += in[base + h + 4 * nb + lane] * wsf[TAPS - 1];

    #pragma unroll
    for (int off = 32; off; off >>= 1) sum += __shfl_xor(sum, off, 64);

    long ob = (long)c * CCH;
    #pragma unroll
    for (int j = 0; j < 4; ++j) {
        int idx = lane + 64 * j;
        if (idx < CCH) out[ob + idx] = sum;
    }
}

// ---------------------------------------------------------------------------
// Fallback (ws too small): weights in LDS, per-element q/237 via const-div.
// ---------------------------------------------------------------------------
__global__ __launch_bounds__(256) void conv_fallback_kernel(
    const float* __restrict__ in,
    const float* __restrict__ p3,
    const float* __restrict__ p4,
    float* __restrict__ out) {
    __shared__ float w[TAPS];
    if (threadIdx.x == 0) {
        float a = p3[0], b = p4[0];
        float lg[TAPS];
        float mx = -3.4e38f;
        for (int i = 0; i < TAPS; ++i) {
            float fi = (float)(i + 1);
            lg[i] = a * fi + b * fi * fi;
            mx = fmaxf(mx, lg[i]);
        }
        float s = 0.f;
        for (int i = 0; i < TAPS; ++i) { lg[i] = expf(lg[i] - mx); s += lg[i]; }
        float inv = 1.0f / s;
        for (int i = 0; i < TAPS; ++i) w[i] = lg[i] * inv;
    }
    __syncthreads();

    int wid  = threadIdx.x >> 6;
    int lane = threadIdx.x & 63;
    int c    = (blockIdx.x << 2) + wid;
    int s    = c & 3;
    int h    = (4 - s) & 3;
    long base = (long)c * CHUNK;
    int nb   = (CHUNK - h) >> 2;
    int tail = (CHUNK - h) & 3;

    const float4* in4 = (const float4*)(in + base + h);
    float4 acc = make_float4(0.f, 0.f, 0.f, 0.f);
    for (int m = lane; m < nb; m += 64) {
        float4 x = in4[m];
        int q0 = h + 4 * m;
        acc.x = fmaf(x.x, w[(q0 + 0) / CCH], acc.x);
        acc.y = fmaf(x.y, w[(q0 + 1) / CCH], acc.y);
        acc.z = fmaf(x.z, w[(q0 + 2) / CCH], acc.z);
        acc.w = fmaf(x.w, w[(q0 + 3) / CCH], acc.w);
    }
    float sum = acc.x + acc.y + acc.z + acc.w;
    if (lane < h)    sum += in[base + lane] * w[0];
    if (lane < tail) sum += in[base + h + 4 * nb + lane] * w[TAPS - 1];

    #pragma unroll
    for (int off = 32; off; off >>= 1) sum += __shfl_xor(sum, off, 64);

    long ob = (long)c * CCH;
    for (int j = lane; j < CCH; j += 64) out[ob + j] = sum;
}

extern "C" void kernel_launch(void* const* d_in, const int* in_sizes, int n_in,
                              void* d_out, int out_size, void* d_ws, size_t ws_size,
                              hipStream_t stream) {
    const float* in = (const float*)d_in[0];
    const float* p3 = (const float*)d_in[1];
    const float* p4 = (const float*)d_in[2];
    float* out = (float*)d_out;

    size_t need = (size_t)(TAB_OFF + 4 * NB_PAD * 4) * sizeof(float);
    if (ws_size >= need && d_ws != nullptr) {
        float* wsf = (float*)d_ws;
        conv_weights_kernel<<<40, 256, 0, stream>>>(p3, p4, wsf);
        conv_main_kernel<<<NCHUNK / 4, 256, 0, stream>>>(in, wsf, out);
    } else {
        conv_fallback_kernel<<<NCHUNK / 4, 256, 0, stream>>>(in, p3, p4, out);
    }
}